// Round 9
// baseline (111.401 us; speedup 1.0000x reference)
//
#include <hip/hip_runtime.h>

// NodeEncoder with interpolation, round 9 (R8 bug-fixed).
//
// R8 bug: CHUNK=2048 but staging wrote only 1024 floats/chunk (one v4f per
// thread) -> upper half of zbuf read uninitialized. Fixed: 8 floats (two
// float4) staged per thread. Topology theory unchanged and now actually
// tested:
//   512 blocks (2/CU), each owning a CONTIGUOUS range of 2048-atom chunks
//   -> one long contiguous ~1 MB write stream + one contiguous read stream
//   per block (fill-kernel-like), reads interrupting writes only every
//   512 KB. Double-buffered zbuf + prefetch + lgkm-only barriers kept.

#define K_TAB 16
#define N_Z   83
#define CHUNK 2048                 // atoms per phase (8 KB z, 512 KB out)
#define BLOCK 256
#define INNER (CHUNK * 4 / BLOCK)  // float4 stores per thread per phase = 32
#define GRID  512                  // 2 blocks/CU: few long streams

typedef float v4f __attribute__((ext_vector_type(4)));

struct zpair { v4f a, b; };        // 8 floats staged per thread per chunk

// Barrier ordering LDS only — does not drain outstanding global stores.
__device__ __forceinline__ void lds_only_barrier() {
    __asm__ volatile("s_waitcnt lgkmcnt(0)" ::: "memory");
    __builtin_amdgcn_s_barrier();
    __builtin_amdgcn_sched_barrier(0);
}

__device__ __forceinline__ zpair load_chunk_z(const float* __restrict__ z_in,
                                              int c, int tid, int n_atoms) {
    const long a0 = (long)c * CHUNK + tid * 8;
    zpair r;
    r.a = (v4f){0.f, 0.f, 0.f, 0.f};
    r.b = (v4f){0.f, 0.f, 0.f, 0.f};
    if (a0 + 7 < n_atoms) {
        r.a = *reinterpret_cast<const v4f*>(&z_in[a0]);
        r.b = *reinterpret_cast<const v4f*>(&z_in[a0 + 4]);
    } else {
#pragma unroll
        for (int e = 0; e < 4; ++e)
            if (a0 + e < n_atoms) r.a[e] = z_in[a0 + e];
#pragma unroll
        for (int e = 0; e < 4; ++e)
            if (a0 + 4 + e < n_atoms) r.b[e] = z_in[a0 + 4 + e];
    }
    return r;   // OOB atoms -> 0 -> lut row 0 (their stores are guarded off)
}

__global__ __launch_bounds__(BLOCK) void node_encode_kernel(
    const float* __restrict__ z_in,
    float* __restrict__ out,
    int n_atoms, int n_chunks)
{
    __shared__ float lut[N_Z][K_TAB];   // 5.3 KB, read-only after init
    __shared__ float zbuf[2][CHUNK];    // 2 x 8 KB double buffer

    const int tid = threadIdx.x;

    // ---- LUT init: threads 0..82 each build one row ----
    constexpr float tab[K_TAB] = {0.f, 1.f, 6.f, 7.f, 8.f, 11.f, 13.f, 14.f,
                                  16.f, 17.f, 26.f, 29.f, 47.f, 78.f, 79.f, 83.f};
    if (tid < N_Z) {
        const float zf = (float)tid;
        int j = 0;
        float zlo = tab[0];
        float zhi = tab[K_TAB - 1];
#pragma unroll
        for (int k = 0; k < K_TAB; ++k) {          // ascending: count < z, track z_lo
            const bool lt = (tab[k] < zf);
            j += lt ? 1 : 0;
            zlo = lt ? tab[k] : zlo;
        }
#pragma unroll
        for (int k = K_TAB - 2; k >= 0; --k) {     // descending: smallest entry >= z
            zhi = (tab[k] >= zf) ? tab[k] : zhi;
        }
        const bool exact = (zhi == zf);
        const float denom = exact ? 1.f : (zhi - zlo);
        const float inv   = 1.f / denom;
        const float whi   = exact ? 1.f : (zf - zlo) * inv;
        const float wlo   = exact ? 0.f : (zhi - zf) * inv;
        int jl = j - (exact ? 0 : 1);
        if (jl < 0) jl = 0;
#pragma unroll
        for (int c = 0; c < K_TAB; ++c) {
            lut[tid][c] = (c == j ? whi : 0.f) + (c == jl ? wlo : 0.f);
        }
    }

    // ---- contiguous chunk range for this block (balanced split) ----
    const int b = blockIdx.x;
    const int q = n_chunks / GRID;
    const int r = n_chunks % GRID;
    const int c_begin = b * q + (b < r ? b : r);
    const int c_end   = c_begin + q + (b < r ? 1 : 0);

    v4f* __restrict__ out4 = reinterpret_cast<v4f*>(out);
    const long total4 = (long)n_atoms * 4;

    // ---- prologue: stage first chunk into zbuf[0] (also publishes LUT) ----
    if (c_begin < c_end) {
        const zpair z0 = load_chunk_z(z_in, c_begin, tid, n_atoms);
        *reinterpret_cast<v4f*>(&zbuf[0][tid * 8])     = z0.a;
        *reinterpret_cast<v4f*>(&zbuf[0][tid * 8 + 4]) = z0.b;
    }
    lds_only_barrier();

    // ---- phase loop: contiguous chunks, stores never drain ----
    int p = 0;
    for (int c = c_begin; c < c_end; ++c, ++p) {
        const bool haveN = (c + 1 < c_end);
        zpair zregN;
        zregN.a = (v4f){0.f, 0.f, 0.f, 0.f};
        zregN.b = (v4f){0.f, 0.f, 0.f, 0.f};
        if (haveN) zregN = load_chunk_z(z_in, c + 1, tid, n_atoms);  // issue early

        const float* __restrict__ zb = zbuf[p & 1];
        const long base4 = (long)c * (CHUNK * 4);
        if (base4 + CHUNK * 4 <= total4) {
#pragma unroll
            for (int k = 0; k < INNER; ++k) {
                const int u  = k * BLOCK + tid;
                const int zi = (int)zb[u >> 2];
                const v4f v  = *reinterpret_cast<const v4f*>(&lut[zi][(u & 3) << 2]);
                out4[base4 + u] = v;
            }
        } else {
            for (int k = 0; k < INNER; ++k) {
                const int u = k * BLOCK + tid;
                const long g = base4 + u;
                if (g < total4) {
                    const int zi = (int)zb[u >> 2];
                    out4[g] = *reinterpret_cast<const v4f*>(&lut[zi][(u & 3) << 2]);
                }
            }
        }

        if (haveN) {
            *reinterpret_cast<v4f*>(&zbuf[(p + 1) & 1][tid * 8])     = zregN.a;
            *reinterpret_cast<v4f*>(&zbuf[(p + 1) & 1][tid * 8 + 4]) = zregN.b;
        }
        lds_only_barrier();
    }
}

extern "C" void kernel_launch(void* const* d_in, const int* in_sizes, int n_in,
                              void* d_out, int out_size, void* d_ws, size_t ws_size,
                              hipStream_t stream) {
    const float* z = (const float*)d_in[0];
    float* out = (float*)d_out;
    const int n_atoms = in_sizes[0];

    const int n_chunks = (n_atoms + CHUNK - 1) / CHUNK;   // 3907

    node_encode_kernel<<<GRID, BLOCK, 0, stream>>>(z, out, n_atoms, n_chunks);
}